// Round 10
// baseline (350.998 us; speedup 1.0000x reference)
//
#include <hip/hip_runtime.h>
#include <stdint.h>

#define BDIM 4
#define CDIM 128
#define NDIM 4096
#define KSEL 10

typedef unsigned long long ull;

// CK-style global->LDS direct copy (16 B/lane).
__device__ __forceinline__ void async_cp16(void* lds, const void* g) {
  auto* gp = (const __attribute__((address_space(1))) unsigned int*)(uintptr_t)g;
  auto* lp = (__attribute__((address_space(3))) unsigned int*)(unsigned int)(uintptr_t)lds;
  __builtin_amdgcn_global_load_lds(gp, lp, 16, 0, 0);
}

// ---------------------------------------------------------------------------
// Kernel A: xx[b][n] = sum_c x[b][c][n]^2
// ---------------------------------------------------------------------------
__global__ __launch_bounds__(256) void xx_kernel(const float* __restrict__ x,
                                                 float* __restrict__ xx) {
  int t = threadIdx.x;
  int nl = t >> 2;
  int part = t & 3;
  int g = blockIdx.x * 64 + nl;      // 0..B*N-1
  int b = g >> 12;
  int n = g & (NDIM - 1);
  const float* xp = x + (size_t)b * CDIM * NDIM + n;
  float s = 0.f;
  int c0 = part * 32;
#pragma unroll
  for (int i = 0; i < 32; ++i) {
    float v = xp[(size_t)(c0 + i) * NDIM];
    s += v * v;
  }
  s += __shfl_xor(s, 1, 4);
  s += __shfl_xor(s, 2, 4);
  if (part == 0) xx[g] = s;
}

// ---------------------------------------------------------------------------
// Kernel W: WT[c][o] = W[o][c]  (256x256, one-time, L2-hot)
// ---------------------------------------------------------------------------
__global__ __launch_bounds__(256) void wtrans_kernel(const float* __restrict__ W,
                                                     float* __restrict__ WT) {
  int c = blockIdx.x, o = threadIdx.x;
  WT[c * 256 + o] = W[o * 256 + c];
}

// ---------------------------------------------------------------------------
// Kernel S: score GEMM, symmetry-halved, multi-batch grid.
// LDS shrunk 40960 -> 32768 B exactly: 5 blocks/CU capacity (was 4, measured
// ~2 resident); allocator's LDS-occupancy target 5 waves/EU -> ~102 VGPR cap,
// still above the ~80-reg demand (R9 allocated 60 VGPR, no spill).
// ---------------------------------------------------------------------------
__global__ __launch_bounds__(256) void score_kernel(const float* __restrict__ x,
                                                    const float* __restrict__ xxg,
                                                    float* __restrict__ scb,
                                                    int b0) {
  const int N = NDIM;
  int bb = b0 + blockIdx.y;
  float* sc = scb + (size_t)blockIdx.y * N * N;
  // triangular decode: block -> (I, J), I<=J
  int p = blockIdx.x;
  int I = 0;
  while (p >= 32 - I) { p -= 32 - I; ++I; }
  int J = I + p;
  int n0 = I * 128, m0 = J * 128;

  int t = threadIdx.x;
  int tx = t & 15, ty = t >> 4;
  int tx4 = tx * 4, ty4 = ty * 4;

  __shared__ float smem[8192];       // 32768 B (8192 f used by staging)
  float* xn_s = smem;                // [32][128]
  float* xm_s = smem + 4096;         // [32][128]

  const float* xb = x + (size_t)bb * CDIM * N;

  float acc[8][8];
#pragma unroll
  for (int i = 0; i < 8; ++i)
#pragma unroll
    for (int j = 0; j < 8; ++j) acc[i][j] = 0.f;

  for (int ch = 0; ch < 4; ++ch) {
    int c0 = ch * 32;
    __syncthreads();
#pragma unroll
    for (int pp = 0; pp < 4; ++pp) {
      int i4 = t + 256 * pp;
      async_cp16(&xn_s[i4 * 4], &xb[(size_t)(c0 + (i4 >> 5)) * N + n0 + (i4 & 31) * 4]);
    }
#pragma unroll
    for (int pp = 0; pp < 4; ++pp) {
      int i4 = t + 256 * pp;
      async_cp16(&xm_s[i4 * 4], &xb[(size_t)(c0 + (i4 >> 5)) * N + m0 + (i4 & 31) * 4]);
    }
    __syncthreads();

#pragma unroll 4
    for (int cc = 0; cc < 32; ++cc) {
      float4 a0 = *(const float4*)&xn_s[cc * 128 + ty4];
      float4 a1 = *(const float4*)&xn_s[cc * 128 + ty4 + 64];
      float4 b0 = *(const float4*)&xm_s[cc * 128 + tx4];
      float4 b1 = *(const float4*)&xm_s[cc * 128 + tx4 + 64];
      float av[8] = {a0.x, a0.y, a0.z, a0.w, a1.x, a1.y, a1.z, a1.w};
      float bv[8] = {b0.x, b0.y, b0.z, b0.w, b1.x, b1.y, b1.z, b1.w};
#pragma unroll
      for (int i = 0; i < 8; ++i)
#pragma unroll
        for (int j = 0; j < 8; ++j) acc[i][j] += av[i] * bv[j];
    }
  }

  const float* xxb = xxg + (size_t)bb * N;

  // epilogue 1: sc[n][m] = 2*acc - xx[m]
  {
    float4 w0 = *(const float4*)&xxb[m0 + tx4];
    float4 w1 = *(const float4*)&xxb[m0 + tx4 + 64];
    float wv[8] = {w0.x, w0.y, w0.z, w0.w, w1.x, w1.y, w1.z, w1.w};
#pragma unroll
    for (int i = 0; i < 8; ++i) {
      int row = n0 + ty4 + (i & 3) + (i >> 2) * 64;
      float* po = sc + (size_t)row * N + m0;
      *(float4*)&po[tx4] =
          make_float4(2.f * acc[i][0] - wv[0], 2.f * acc[i][1] - wv[1],
                      2.f * acc[i][2] - wv[2], 2.f * acc[i][3] - wv[3]);
      *(float4*)&po[tx4 + 64] =
          make_float4(2.f * acc[i][4] - wv[4], 2.f * acc[i][5] - wv[5],
                      2.f * acc[i][6] - wv[6], 2.f * acc[i][7] - wv[7]);
    }
  }

  // epilogue 2 (off-diag only): sc[m][n] = 2*acc - xx[n]
  if (J != I) {
    float4 u0 = *(const float4*)&xxb[n0 + ty4];
    float4 u1 = *(const float4*)&xxb[n0 + ty4 + 64];
    float uv[8] = {u0.x, u0.y, u0.z, u0.w, u1.x, u1.y, u1.z, u1.w};
#pragma unroll
    for (int j = 0; j < 8; ++j) {
      int col = m0 + tx4 + (j & 3) + (j >> 2) * 64;
      float* po = sc + (size_t)col * N + n0;
      *(float4*)&po[ty4] =
          make_float4(2.f * acc[0][j] - uv[0], 2.f * acc[1][j] - uv[1],
                      2.f * acc[2][j] - uv[2], 2.f * acc[3][j] - uv[3]);
      *(float4*)&po[ty4 + 64] =
          make_float4(2.f * acc[4][j] - uv[4], 2.f * acc[5][j] - uv[5],
                      2.f * acc[6][j] - uv[6], 2.f * acc[7][j] - uv[7]);
    }
  }
}

// ---------------------------------------------------------------------------
// Kernel T v3: float-domain top-10 scan. One wave per row.
// Phase A: per-lane branchless top-2 on raw f32 (finite, no NaN): 2 cmp +
//   6 cndmask per element (vs ~15 VALU for the u64-key version). Strict '>'
//   keeps the earlier (= smaller m, ascending scan) on value ties.
// Phase B: 10 rounds: f32 butterfly max -> min-index butterfly among tied
//   lanes (exact jax (val desc, idx asc) semantics). Lane exhaustion rescans
//   strictly after (mxv, mnidx) — exact, rare (~0.7 lanes/row).
// ---------------------------------------------------------------------------
__global__ __launch_bounds__(256) void scan_kernel(const float* __restrict__ scb,
                                                   int* __restrict__ idxout,
                                                   int b0) {
  int t = threadIdx.x;
  int lane = t & 63;
  int w = t >> 6;
  int row = blockIdx.x * 4 + w;
  int bb = b0 + blockIdx.y;
  const float4* srow =
      (const float4*)(scb + (size_t)blockIdx.y * NDIM * NDIM + (size_t)row * NDIM);

  float k1v = -3e38f, k2v = -3e38f;
  int i1 = -1, i2 = -1;
  int base = lane * 4;

#pragma unroll 4
  for (int j4 = 0; j4 < 16; ++j4) {
    float4 q = srow[j4 * 64 + lane];
    float vv[4] = {q.x, q.y, q.z, q.w};
#pragma unroll
    for (int e = 0; e < 4; ++e) {
      float v = vv[e];
      int idx = base + (j4 << 8) + e;
      bool gt1 = v > k1v;
      bool gt2 = v > k2v;
      k2v = gt1 ? k1v : (gt2 ? v : k2v);
      i2 = gt1 ? i1 : (gt2 ? idx : i2);
      k1v = gt1 ? v : k1v;
      i1 = gt1 ? idx : i1;
    }
  }

  int my = 0;
  for (int s = 0; s < KSEL; ++s) {
    float mxv = k1v;
#pragma unroll
    for (int off = 1; off < 64; off <<= 1) {
      float o = __shfl_xor(mxv, off);
      mxv = o > mxv ? o : mxv;
    }
    bool elig = (k1v == mxv);
    unsigned mn = elig ? (unsigned)i1 : 0xFFFFFFFFu;
#pragma unroll
    for (int off = 1; off < 64; off <<= 1) {
      unsigned o = __shfl_xor(mn, off);
      mn = o < mn ? o : mn;
    }
    if (elig && (unsigned)i1 == mn) {  // unique winner lane
      if (i2 >= 0) {
        k1v = k2v; i1 = i2;
        k2v = -3e38f; i2 = -1;
      } else {
        // rescan strictly after (mxv, mn) in (val desc, idx asc) order
        float r1v = -3e38f, r2v = -3e38f;
        int r1i = -1, r2i = -1;
        for (int j4 = 0; j4 < 16; ++j4) {
          float4 q = srow[j4 * 64 + lane];
          float vv[4] = {q.x, q.y, q.z, q.w};
#pragma unroll
          for (int e = 0; e < 4; ++e) {
            float v = vv[e];
            int idx = base + (j4 << 8) + e;
            if (v < mxv || (v == mxv && (unsigned)idx > mn)) {
              bool g1 = v > r1v;
              bool g2 = v > r2v;
              r2v = g1 ? r1v : (g2 ? v : r2v);
              r2i = g1 ? r1i : (g2 ? idx : r2i);
              r1v = g1 ? v : r1v;
              r1i = g1 ? idx : r1i;
            }
          }
        }
        k1v = r1v; i1 = r1i;
        k2v = r2v; i2 = r2i;
      }
    }
    if (lane == s) my = (int)mn;
  }
  if (lane < KSEL)
    idxout[((size_t)bb * NDIM + row) * KSEL + lane] = my;
}

// ---------------------------------------------------------------------------
// Kernel C: Md[b][c][n] = mean_k x[b][c][idx[b][n][k]] - x[b][c][n]
// ---------------------------------------------------------------------------
__global__ __launch_bounds__(256) void gather_kernel(const float* __restrict__ x,
                                                     const int* __restrict__ idxg,
                                                     float* __restrict__ Md) {
  const int N = NDIM;
  int bb = blockIdx.y, c = blockIdx.x;
  __shared__ float row_s[NDIM];
  const float* rowg = x + (size_t)(bb * CDIM + c) * N;
  int t = threadIdx.x;
#pragma unroll
  for (int p = 0; p < 4; ++p) {
    int i4 = t + 256 * p;
    *(float4*)&row_s[i4 * 4] = *(const float4*)&rowg[i4 * 4];
  }
  __syncthreads();
  float* outp = Md + (size_t)(bb * CDIM + c) * N;
  const int* ib = idxg + (size_t)bb * N * KSEL;
  for (int p = 0; p < 16; ++p) {
    int n = t + 256 * p;
    const int* ip = ib + (size_t)n * KSEL;
    float s = 0.f;
#pragma unroll
    for (int k = 0; k < KSEL; ++k) s += row_s[ip[k]];
    outp[n] = s * 0.1f - row_s[n];
  }
}

// ---------------------------------------------------------------------------
// Kernel D v2: out via pre-transposed WT (R9-proven).
// ---------------------------------------------------------------------------
__global__ __launch_bounds__(256) void out_kernel(const float* __restrict__ Md,
                                                  const float* __restrict__ x,
                                                  const float* __restrict__ WT,
                                                  const float* __restrict__ bias,
                                                  float* __restrict__ out) {
  const int N = NDIM, O = 256;
  int bb = blockIdx.z;
  int o0 = blockIdx.y * 64;
  int n0 = blockIdx.x * 128;
  int t = threadIdx.x;
  int tx = t & 15, ty = t >> 4;
  int tx4 = tx * 4, ty4 = ty * 4;

  __shared__ float smem[10240];      // 40960 B (proven R9 profile)
  float* wt_s = smem;                // [32][64]
  float* src_s = smem + 2048;        // [32][128]

  float acc[4][8];
#pragma unroll
  for (int i = 0; i < 4; ++i)
#pragma unroll
    for (int j = 0; j < 8; ++j) acc[i][j] = 0.f;

  for (int ch = 0; ch < 8; ++ch) {
    const float* src = (ch < 4)
        ? Md + (size_t)(bb * CDIM + ch * 32) * N
        : x + (size_t)(bb * CDIM + (ch - 4) * 32) * N;
    __syncthreads();
#pragma unroll
    for (int p = 0; p < 2; ++p) {
      int i4 = t + 256 * p;
      async_cp16(&wt_s[i4 * 4], &WT[(size_t)(ch * 32 + (i4 >> 4)) * O + o0 + (i4 & 15) * 4]);
    }
#pragma unroll
    for (int p = 0; p < 4; ++p) {
      int i4 = t + 256 * p;
      async_cp16(&src_s[i4 * 4], &src[(size_t)(i4 >> 5) * N + n0 + (i4 & 31) * 4]);
    }
    __syncthreads();

#pragma unroll 4
    for (int cc = 0; cc < 32; ++cc) {
      float4 a = *(const float4*)&wt_s[cc * 64 + ty4];
      float4 b0 = *(const float4*)&src_s[cc * 128 + tx4];
      float4 b1 = *(const float4*)&src_s[cc * 128 + tx4 + 64];
      float av[4] = {a.x, a.y, a.z, a.w};
      float bv[8] = {b0.x, b0.y, b0.z, b0.w, b1.x, b1.y, b1.z, b1.w};
#pragma unroll
      for (int i = 0; i < 4; ++i)
#pragma unroll
        for (int j = 0; j < 8; ++j) acc[i][j] += av[i] * bv[j];
    }
  }

#pragma unroll
  for (int i = 0; i < 4; ++i) {
    int o = o0 + ty4 + i;
    float bv = bias[o];
    float* po = out + (size_t)(bb * O + o) * N + n0;
    *(float4*)&po[tx4] = make_float4(acc[i][0] + bv, acc[i][1] + bv,
                                     acc[i][2] + bv, acc[i][3] + bv);
    *(float4*)&po[tx4 + 64] = make_float4(acc[i][4] + bv, acc[i][5] + bv,
                                          acc[i][6] + bv, acc[i][7] + bv);
  }
}

// ---------------------------------------------------------------------------
extern "C" void kernel_launch(void* const* d_in, const int* in_sizes, int n_in,
                              void* d_out, int out_size, void* d_ws, size_t ws_size,
                              hipStream_t stream) {
  const float* x = (const float*)d_in[0];     // (4,128,4096) fp32
  const float* W = (const float*)d_in[1];     // (256,256,1,1) fp32
  const float* bias = (const float*)d_in[2];  // (256,) fp32
  float* out = (float*)d_out;                 // (4,256,4096) fp32

  // ws carve: xx 64K | idx 640K | Md 8M | sc (nb x 64M) ... | WT 256K at top
  float* xx = (float*)d_ws;
  int* idx = (int*)((char*)d_ws + 65536);
  float* Md = (float*)((char*)d_ws + 65536 + 655360);
  const size_t fixed = 9109504;
  float* sc = (float*)((char*)d_ws + fixed);
  size_t wt_off = (ws_size - 262144) & ~(size_t)255;
  float* WT = (float*)((char*)d_ws + wt_off);

  const size_t per_b = (size_t)NDIM * NDIM * 4;
  int nb = 1;
  if (fixed + 4 * per_b <= wt_off) nb = 4;
  else if (fixed + 2 * per_b <= wt_off) nb = 2;

  xx_kernel<<<dim3(256), 256, 0, stream>>>(x, xx);
  wtrans_kernel<<<dim3(256), 256, 0, stream>>>(W, WT);
  for (int b0 = 0; b0 < BDIM; b0 += nb) {
    score_kernel<<<dim3(528, nb), 256, 0, stream>>>(x, xx, sc, b0);
    scan_kernel<<<dim3(1024, nb), 256, 0, stream>>>(sc, idx, b0);
  }
  gather_kernel<<<dim3(128, 4), 256, 0, stream>>>(x, idx, Md);
  out_kernel<<<dim3(32, 4, 4), 256, 0, stream>>>(Md, x, WT, bias, out);
}

// Round 11
// 292.203 us; speedup vs baseline: 1.2012x; 1.2012x over previous
//
#include <hip/hip_runtime.h>
#include <stdint.h>

#define BDIM 4
#define CDIM 128
#define NDIM 4096
#define KSEL 10

typedef unsigned long long ull;

// CK-style global->LDS direct copy (16 B/lane).
__device__ __forceinline__ void async_cp16(void* lds, const void* g) {
  auto* gp = (const __attribute__((address_space(1))) unsigned int*)(uintptr_t)g;
  auto* lp = (__attribute__((address_space(3))) unsigned int*)(unsigned int)(uintptr_t)lds;
  __builtin_amdgcn_global_load_lds(gp, lp, 16, 0, 0);
}

__device__ __forceinline__ ull umax64(ull a, ull b) { return a > b ? a : b; }
__device__ __forceinline__ ull umin64(ull a, ull b) { return a > b ? b : a; }

// merge two sorted-desc pairs (a0>=a1),(b0>=b1) -> sorted top-2 of union
__device__ __forceinline__ void merge2(ull& a0, ull& a1, ull b0, ull b1) {
  ull c0 = umax64(a0, b0);
  ull c1 = umax64(umin64(a0, b0), umax64(a1, b1));
  a0 = c0; a1 = c1;
}

__device__ __forceinline__ ull makekey(float s, unsigned low) {
  unsigned u = __float_as_uint(s);
  unsigned mono = u ^ ((unsigned)(((int)u) >> 31) | 0x80000000u);
  return ((ull)mono << 32) | (ull)low;
}

// ---------------------------------------------------------------------------
// Kernel A: xx[b][n] = sum_c x[b][c][n]^2
// ---------------------------------------------------------------------------
__global__ __launch_bounds__(256) void xx_kernel(const float* __restrict__ x,
                                                 float* __restrict__ xx) {
  int t = threadIdx.x;
  int nl = t >> 2;
  int part = t & 3;
  int g = blockIdx.x * 64 + nl;
  int b = g >> 12;
  int n = g & (NDIM - 1);
  const float* xp = x + (size_t)b * CDIM * NDIM + n;
  float s = 0.f;
  int c0 = part * 32;
#pragma unroll
  for (int i = 0; i < 32; ++i) {
    float v = xp[(size_t)(c0 + i) * NDIM];
    s += v * v;
  }
  s += __shfl_xor(s, 1, 4);
  s += __shfl_xor(s, 2, 4);
  if (part == 0) xx[g] = s;
}

// ---------------------------------------------------------------------------
// Kernel W: WT[c][o] = W[o][c]
// ---------------------------------------------------------------------------
__global__ __launch_bounds__(256) void wtrans_kernel(const float* __restrict__ W,
                                                     float* __restrict__ WT) {
  int c = blockIdx.x, o = threadIdx.x;
  WT[c * 256 + o] = W[o * 256 + c];
}

// ---------------------------------------------------------------------------
// Kernel S: score GEMM (symmetry-halved) -> per-(row, 64-col-group) top-2
// candidate keys. NO sc matrix. pc[row][64][2] u64 per batch (4 MB vs 64 MB).
// Key = mono(score)<<32 | (4095-m): (val desc, idx asc) exact order.
// n-side: thread top-2-of-4 per quad, 4-round shuffle merge across tx lanes.
// m-side (off-diag): 2 in-wave ty rounds + LDS cross-wave merge (16 KB reuse).
// ---------------------------------------------------------------------------
__global__ __launch_bounds__(256) void score_kernel(const float* __restrict__ x,
                                                    const float* __restrict__ xxg,
                                                    ull* __restrict__ pcall) {
  const int N = NDIM;
  int bb = blockIdx.y;
  ull* pcb = pcall + (size_t)bb * N * 128;
  int p = blockIdx.x;
  int I = 0;
  while (p >= 32 - I) { p -= 32 - I; ++I; }
  int J = I + p;
  int n0 = I * 128, m0 = J * 128;

  int t = threadIdx.x;
  int tx = t & 15, ty = t >> 4;
  int tx4 = tx * 4, ty4 = ty * 4;

  __shared__ float smem[10240];      // 40960 B (R9-proven no-spill profile)
  float* xn_s = smem;                // [32][128]
  float* xm_s = smem + 4096;         // [32][128]

  const float* xb = x + (size_t)bb * CDIM * N;

  float acc[8][8];
#pragma unroll
  for (int i = 0; i < 8; ++i)
#pragma unroll
    for (int j = 0; j < 8; ++j) acc[i][j] = 0.f;

  for (int ch = 0; ch < 4; ++ch) {
    int c0 = ch * 32;
    __syncthreads();
#pragma unroll
    for (int pp = 0; pp < 4; ++pp) {
      int i4 = t + 256 * pp;
      async_cp16(&xn_s[i4 * 4], &xb[(size_t)(c0 + (i4 >> 5)) * N + n0 + (i4 & 31) * 4]);
    }
#pragma unroll
    for (int pp = 0; pp < 4; ++pp) {
      int i4 = t + 256 * pp;
      async_cp16(&xm_s[i4 * 4], &xb[(size_t)(c0 + (i4 >> 5)) * N + m0 + (i4 & 31) * 4]);
    }
    __syncthreads();

#pragma unroll 4
    for (int cc = 0; cc < 32; ++cc) {
      float4 a0 = *(const float4*)&xn_s[cc * 128 + ty4];
      float4 a1 = *(const float4*)&xn_s[cc * 128 + ty4 + 64];
      float4 b0 = *(const float4*)&xm_s[cc * 128 + tx4];
      float4 b1 = *(const float4*)&xm_s[cc * 128 + tx4 + 64];
      float av[8] = {a0.x, a0.y, a0.z, a0.w, a1.x, a1.y, a1.z, a1.w};
      float bv[8] = {b0.x, b0.y, b0.z, b0.w, b1.x, b1.y, b1.z, b1.w};
#pragma unroll
      for (int i = 0; i < 8; ++i)
#pragma unroll
        for (int j = 0; j < 8; ++j) acc[i][j] += av[i] * bv[j];
    }
  }

  const float* xxb = xxg + (size_t)bb * N;

  // ----- n-side: rows n0.., groups 2J,2J+1 -----
  {
    float4 w0 = *(const float4*)&xxb[m0 + tx4];
    float4 w1 = *(const float4*)&xxb[m0 + tx4 + 64];
    float xv[8] = {w0.x, w0.y, w0.z, w0.w, w1.x, w1.y, w1.z, w1.w};
    unsigned mlow[8];
#pragma unroll
    for (int j = 0; j < 8; ++j)
      mlow[j] = 4095u - (unsigned)(m0 + tx4 + (j & 3) + (j >> 2) * 64);
#pragma unroll
    for (int i = 0; i < 8; ++i) {
      ull k[8];
#pragma unroll
      for (int j = 0; j < 8; ++j)
        k[j] = makekey(__builtin_fmaf(2.f, acc[i][j], -xv[j]), mlow[j]);
      ull g0a = umax64(k[0], k[1]), g0b = umin64(k[0], k[1]);
      merge2(g0a, g0b, umax64(k[2], k[3]), umin64(k[2], k[3]));
      ull g1a = umax64(k[4], k[5]), g1b = umin64(k[4], k[5]);
      merge2(g1a, g1b, umax64(k[6], k[7]), umin64(k[6], k[7]));
#pragma unroll
      for (int off = 1; off < 16; off <<= 1) {
        ull p0 = __shfl_xor(g0a, off), p1 = __shfl_xor(g0b, off);
        merge2(g0a, g0b, p0, p1);
        ull q0 = __shfl_xor(g1a, off), q1 = __shfl_xor(g1b, off);
        merge2(g1a, g1b, q0, q1);
      }
      if (tx == 0) {
        int row = n0 + ty4 + (i & 3) + (i >> 2) * 64;
        ull* pr = pcb + (size_t)row * 128;
        ulonglong2 v0; v0.x = g0a; v0.y = g0b;
        ulonglong2 v1; v1.x = g1a; v1.y = g1b;
        *(ulonglong2*)&pr[(2 * J) * 2] = v0;
        *(ulonglong2*)&pr[(2 * J + 1) * 2] = v1;
      }
    }
  }

  // ----- m-side (off-diag): rows m0.., groups 2I,2I+1 -----
  if (J != I) {
    __syncthreads();  // GEMM LDS reads done; reuse smem for merge scratch
    ull* lm = (ull*)smem;  // [128 lr][4 wave][2 g][2] = 2048 u64 = 16 KB
    float4 u0 = *(const float4*)&xxb[n0 + ty4];
    float4 u1 = *(const float4*)&xxb[n0 + ty4 + 64];
    float uv[8] = {u0.x, u0.y, u0.z, u0.w, u1.x, u1.y, u1.z, u1.w};
    unsigned nlow[8];
#pragma unroll
    for (int i = 0; i < 8; ++i)
      nlow[i] = 4095u - (unsigned)(n0 + ty4 + (i & 3) + (i >> 2) * 64);
    int wv = t >> 6;
#pragma unroll
    for (int j = 0; j < 8; ++j) {
      ull k[8];
#pragma unroll
      for (int i = 0; i < 8; ++i)
        k[i] = makekey(__builtin_fmaf(2.f, acc[i][j], -uv[i]), nlow[i]);
      ull g0a = umax64(k[0], k[1]), g0b = umin64(k[0], k[1]);
      merge2(g0a, g0b, umax64(k[2], k[3]), umin64(k[2], k[3]));
      ull g1a = umax64(k[4], k[5]), g1b = umin64(k[4], k[5]);
      merge2(g1a, g1b, umax64(k[6], k[7]), umin64(k[6], k[7]));
#pragma unroll
      for (int off = 16; off < 64; off <<= 1) {
        ull p0 = __shfl_xor(g0a, off), p1 = __shfl_xor(g0b, off);
        merge2(g0a, g0b, p0, p1);
        ull q0 = __shfl_xor(g1a, off), q1 = __shfl_xor(g1b, off);
        merge2(g1a, g1b, q0, q1);
      }
      if ((ty & 3) == 0) {
        int lr = tx4 + (j & 3) + (j >> 2) * 64;
        lm[lr * 16 + wv * 4 + 0] = g0a;
        lm[lr * 16 + wv * 4 + 1] = g0b;
        lm[lr * 16 + wv * 4 + 2] = g1a;
        lm[lr * 16 + wv * 4 + 3] = g1b;
      }
    }
    __syncthreads();
    {
      int lr = t >> 1, g = t & 1;
      ull c0 = lm[lr * 16 + 0 + g * 2], c1 = lm[lr * 16 + 0 + g * 2 + 1];
#pragma unroll
      for (int w2 = 1; w2 < 4; ++w2)
        merge2(c0, c1, lm[lr * 16 + w2 * 4 + g * 2], lm[lr * 16 + w2 * 4 + g * 2 + 1]);
      int row = m0 + lr;
      ulonglong2 v; v.x = c0; v.y = c1;
      *(ulonglong2*)&pcb[(size_t)row * 128 + (2 * I + g) * 2] = v;
    }
  }
}

// ---------------------------------------------------------------------------
// Kernel M: exact top-10 from candidates. One wave per row; lane = group
// (64 cols each), holds the group's sorted top-2. 10 butterfly-argmax rounds;
// on lane exhaustion the wave recomputes that group's 64 scores from x
// (bitwise-identical fmaf chain), filters key<mx (+orig-idx exclusion),
// top-2 reduces, refills. Exact (hidden 3rd < stored 2nd <= extracted mx).
// ---------------------------------------------------------------------------
__global__ __launch_bounds__(256) void merge_kernel(const float* __restrict__ x,
                                                    const float* __restrict__ xxg,
                                                    const ull* __restrict__ pcall,
                                                    int* __restrict__ idxout) {
  int t = threadIdx.x;
  int lane = t & 63;
  int wv = t >> 6;
  int bb = blockIdx.y;
  int row = blockIdx.x * 4 + wv;
  const ull* pr = pcall + ((size_t)bb * NDIM + row) * 128;
  ulonglong2 c = ((const ulonglong2*)pr)[lane];
  ull c1 = c.x, c2 = c.y;
  unsigned orig0 = (unsigned)(c1 & 0xFFFFFFFFull);
  unsigned orig1 = (unsigned)(c2 & 0xFFFFFFFFull);

  const float* xb = x + (size_t)bb * CDIM * NDIM;
  const float* xxb = xxg + (size_t)bb * NDIM;

  // stage this row's x column (x[c][row], c=0..127) for rescan reuse
  __shared__ float xrow_s[4 * 128];
  xrow_s[wv * 128 + lane] = xb[(size_t)lane * NDIM + row];
  xrow_s[wv * 128 + 64 + lane] = xb[(size_t)(64 + lane) * NDIM + row];

  int my = 0;
  for (int s = 0; s < KSEL; ++s) {
    ull mx = c1;
#pragma unroll
    for (int off = 1; off < 64; off <<= 1) {
      ull o = __shfl_xor(mx, off);
      mx = o > mx ? o : mx;
    }
    if (lane == s) my = 4095 - (int)(unsigned)(mx & 0xFFFFFFFFull);
    if (s < KSEL - 1) {
      bool iswin = (c1 == mx);
      ull bal = __ballot(iswin && (c2 == 0ull));
      if (iswin) { c1 = c2; c2 = 0ull; }
      if (bal) {
        int g = (int)(__ffsll((long long)bal) - 1);
        unsigned e0 = __shfl(orig0, g), e1 = __shfl(orig1, g);
        int col = g * 64 + lane;
        const float* xc = xb + col;
        const float* xrs = xrow_s + wv * 128;
        float d = 0.f;
        for (int cc = 0; cc < 128; ++cc)
          d = __builtin_fmaf(xc[(size_t)cc * NDIM], xrs[cc], d);
        float sv = __builtin_fmaf(2.f, d, -xxb[col]);
        unsigned low = 4095u - (unsigned)col;
        ull key = makekey(sv, low);
        if (key >= mx || low == e0 || low == e1) key = 0ull;
        ull r1 = key;
#pragma unroll
        for (int off = 1; off < 64; off <<= 1) {
          ull o = __shfl_xor(r1, off);
          r1 = o > r1 ? o : r1;
        }
        ull key2 = (key == r1) ? 0ull : key;
        ull r2 = key2;
#pragma unroll
        for (int off = 1; off < 64; off <<= 1) {
          ull o = __shfl_xor(r2, off);
          r2 = o > r2 ? o : r2;
        }
        if (lane == g) { c1 = r1; c2 = r2; }
      }
    }
  }
  if (lane < KSEL)
    idxout[((size_t)bb * NDIM + row) * KSEL + lane] = my;
}

// ---------------------------------------------------------------------------
// Kernel C: Md[b][c][n] = mean_k x[b][c][idx[b][n][k]] - x[b][c][n]
// ---------------------------------------------------------------------------
__global__ __launch_bounds__(256) void gather_kernel(const float* __restrict__ x,
                                                     const int* __restrict__ idxg,
                                                     float* __restrict__ Md) {
  const int N = NDIM;
  int bb = blockIdx.y, c = blockIdx.x;
  __shared__ float row_s[NDIM];
  const float* rowg = x + (size_t)(bb * CDIM + c) * N;
  int t = threadIdx.x;
#pragma unroll
  for (int p = 0; p < 4; ++p) {
    int i4 = t + 256 * p;
    *(float4*)&row_s[i4 * 4] = *(const float4*)&rowg[i4 * 4];
  }
  __syncthreads();
  float* outp = Md + (size_t)(bb * CDIM + c) * N;
  const int* ib = idxg + (size_t)bb * N * KSEL;
  for (int p = 0; p < 16; ++p) {
    int n = t + 256 * p;
    const int* ip = ib + (size_t)n * KSEL;
    float s = 0.f;
#pragma unroll
    for (int k = 0; k < KSEL; ++k) s += row_s[ip[k]];
    outp[n] = s * 0.1f - row_s[n];
  }
}

// ---------------------------------------------------------------------------
// Kernel D: out via pre-transposed WT (R9-proven).
// ---------------------------------------------------------------------------
__global__ __launch_bounds__(256) void out_kernel(const float* __restrict__ Md,
                                                  const float* __restrict__ x,
                                                  const float* __restrict__ WT,
                                                  const float* __restrict__ bias,
                                                  float* __restrict__ out) {
  const int N = NDIM, O = 256;
  int bb = blockIdx.z;
  int o0 = blockIdx.y * 64;
  int n0 = blockIdx.x * 128;
  int t = threadIdx.x;
  int tx = t & 15, ty = t >> 4;
  int tx4 = tx * 4, ty4 = ty * 4;

  __shared__ float smem[10240];
  float* wt_s = smem;                // [32][64]
  float* src_s = smem + 2048;        // [32][128]

  float acc[4][8];
#pragma unroll
  for (int i = 0; i < 4; ++i)
#pragma unroll
    for (int j = 0; j < 8; ++j) acc[i][j] = 0.f;

  for (int ch = 0; ch < 8; ++ch) {
    const float* src = (ch < 4)
        ? Md + (size_t)(bb * CDIM + ch * 32) * N
        : x + (size_t)(bb * CDIM + (ch - 4) * 32) * N;
    __syncthreads();
#pragma unroll
    for (int p = 0; p < 2; ++p) {
      int i4 = t + 256 * p;
      async_cp16(&wt_s[i4 * 4], &WT[(size_t)(ch * 32 + (i4 >> 4)) * O + o0 + (i4 & 15) * 4]);
    }
#pragma unroll
    for (int p = 0; p < 4; ++p) {
      int i4 = t + 256 * p;
      async_cp16(&src_s[i4 * 4], &src[(size_t)(i4 >> 5) * N + n0 + (i4 & 31) * 4]);
    }
    __syncthreads();

#pragma unroll 4
    for (int cc = 0; cc < 32; ++cc) {
      float4 a = *(const float4*)&wt_s[cc * 64 + ty4];
      float4 b0 = *(const float4*)&src_s[cc * 128 + tx4];
      float4 b1 = *(const float4*)&src_s[cc * 128 + tx4 + 64];
      float av[4] = {a.x, a.y, a.z, a.w};
      float bv[8] = {b0.x, b0.y, b0.z, b0.w, b1.x, b1.y, b1.z, b1.w};
#pragma unroll
      for (int i = 0; i < 4; ++i)
#pragma unroll
        for (int j = 0; j < 8; ++j) acc[i][j] += av[i] * bv[j];
    }
  }

#pragma unroll
  for (int i = 0; i < 4; ++i) {
    int o = o0 + ty4 + i;
    float bv = bias[o];
    float* po = out + (size_t)(bb * O + o) * N + n0;
    *(float4*)&po[tx4] = make_float4(acc[i][0] + bv, acc[i][1] + bv,
                                     acc[i][2] + bv, acc[i][3] + bv);
    *(float4*)&po[tx4 + 64] = make_float4(acc[i][4] + bv, acc[i][5] + bv,
                                          acc[i][6] + bv, acc[i][7] + bv);
  }
}

// ---------------------------------------------------------------------------
extern "C" void kernel_launch(void* const* d_in, const int* in_sizes, int n_in,
                              void* d_out, int out_size, void* d_ws, size_t ws_size,
                              hipStream_t stream) {
  const float* x = (const float*)d_in[0];     // (4,128,4096) fp32
  const float* W = (const float*)d_in[1];     // (256,256,1,1) fp32
  const float* bias = (const float*)d_in[2];  // (256,) fp32
  float* out = (float*)d_out;                 // (4,256,4096) fp32

  // ws carve: xx 64K | idx 640K | Md 8M | pc 4x4M | WT 256K at top
  float* xx = (float*)d_ws;
  int* idx = (int*)((char*)d_ws + 65536);
  float* Md = (float*)((char*)d_ws + 65536 + 655360);
  const size_t fixed = 9109504;
  ull* pc = (ull*)((char*)d_ws + fixed);      // 4 batches x 4096x128 u64 = 16 MB
  size_t wt_off = (ws_size - 262144) & ~(size_t)255;
  float* WT = (float*)((char*)d_ws + wt_off);

  xx_kernel<<<dim3(256), 256, 0, stream>>>(x, xx);
  wtrans_kernel<<<dim3(256), 256, 0, stream>>>(W, WT);
  score_kernel<<<dim3(528, 4), 256, 0, stream>>>(x, xx, pc);
  merge_kernel<<<dim3(1024, 4), 256, 0, stream>>>(x, xx, pc, idx);
  gather_kernel<<<dim3(128, 4), 256, 0, stream>>>(x, idx, Md);
  out_kernel<<<dim3(32, 4, 4), 256, 0, stream>>>(Md, x, WT, bias, out);
}